// Round 1
// 272.504 us; speedup vs baseline: 1.0358x; 1.0358x over previous
//
#include <hip/hip_runtime.h>

// Problem constants (fixed by the reference)
#define B_N   8
#define S_N   2048
#define K_N   21
#define L_N   16
#define CM_N  256
#define SCHUNK 128
#define CHUNKS (S_N / SCHUNK)   // 16
#define WSTRIDE 260              // floats: 1040 B row stride -> 16B-aligned rows, bank-spread

typedef float vfloat4 __attribute__((ext_vector_type(4)));

__global__ __launch_bounds__(256, 4) void pssm_proj_kernel(
    const float* __restrict__ x,     // [B,S,K]
    const float* __restrict__ W,     // [L,CM,K]
    const float* __restrict__ bias,  // [L,CM]
    float* __restrict__ out)         // [B,L,S,CM]
{
    // x rows staged in LDS, padded to 24 floats so each row is float4-aligned
    __shared__ float xs[SCHUNK][24];
    // W[l] staged TRANSPOSED: wt[k][c] = W[l][c][k].
    // Staged with coalesced global reads (336 cache lines/block) instead of the
    // old per-lane fragment loads (84 VMEM instrs x 64 scattered lines each).
    __shared__ float wt[K_N][WSTRIDE];

    const int tid   = threadIdx.x;
    const int bx    = blockIdx.x;
    const int chunk = bx % CHUNKS;
    const int l     = (bx / CHUNKS) % L_N;
    const int b     = bx / (CHUNKS * L_N);
    const int s0    = chunk * SCHUNK;

    // ---- stage x[b, s0:s0+SCHUNK, 0:21] -> LDS (coalesced fp32 loads) ----
    const float* xbase = x + ((size_t)b * S_N + s0) * K_N;
    for (int idx = tid; idx < SCHUNK * K_N; idx += 256) {
        int r = idx / K_N;
        int k = idx - r * K_N;
        xs[r][k] = xbase[idx];
    }

    // ---- stage W[l] -> LDS transposed (coalesced reads, ~2-3-way write conflicts once) ----
    const float* wbase = W + (size_t)l * CM_N * K_N;   // 5376 floats
    for (int idx = tid; idx < CM_N * K_N; idx += 256) {
        int c = idx / K_N;
        int k = idx - c * K_N;
        wt[k][c] = wbase[idx];
    }

    __syncthreads();

    // ---- per-lane W fragment from LDS: 21 conflict-free ds_read_b128 ----
    const int lane = tid & 63;
    const int wave = tid >> 6;
    const int c0   = lane * 4;

    vfloat4 wfv[K_N];   // wfv[k] = { W[l][c0+0][k], ..., W[l][c0+3][k] }
#pragma unroll
    for (int k = 0; k < K_N; ++k)
        wfv[k] = *(const vfloat4*)(&wt[k][c0]);   // rows 16B-aligned, lanes contiguous 1KB

    vfloat4 bv = *(const vfloat4*)(bias + l * CM_N + c0);  // 16B-aligned coalesced

    float* outbase = out + (((size_t)b * L_N + l) * S_N + s0) * CM_N + c0;

    // each wave sweeps rows {wave, wave+4, ...}: 32 rows/wave
    for (int i = 0; i < SCHUNK / 4; ++i) {
        const int r = i * 4 + wave;
        const vfloat4* xv = (const vfloat4*)(&xs[r][0]);  // wave-uniform broadcast reads

        float a0 = bv.x, a1 = bv.y, a2 = bv.z, a3 = bv.w;
#pragma unroll
        for (int kb = 0; kb < 6; ++kb) {
            vfloat4 xq = xv[kb];
            float xe[4] = {xq.x, xq.y, xq.z, xq.w};
#pragma unroll
            for (int e = 0; e < 4; ++e) {
                const int k = kb * 4 + e;
                if (k < K_N) {   // compile-time guard (K=21 < 24 pad; tail unused)
                    a0 += xe[e] * wfv[k].x;
                    a1 += xe[e] * wfv[k].y;
                    a2 += xe[e] * wfv[k].z;
                    a3 += xe[e] * wfv[k].w;
                }
            }
        }

        // plain streaming store: fill kernel proves this path sustains 6.33 TB/s (79% peak);
        // the nt path was the unproven one. Live LDS/L2 working set is tiny, eviction is fine.
        vfloat4 o = {a0, a1, a2, a3};
        *(vfloat4*)(outbase + (size_t)r * CM_N) = o;
    }
}

extern "C" void kernel_launch(void* const* d_in, const int* in_sizes, int n_in,
                              void* d_out, int out_size, void* d_ws, size_t ws_size,
                              hipStream_t stream) {
    const float* x    = (const float*)d_in[0];
    const float* W    = (const float*)d_in[1];
    const float* bias = (const float*)d_in[2];
    float* out        = (float*)d_out;

    dim3 grid(B_N * L_N * CHUNKS);   // 8*16*16 = 2048 blocks
    dim3 block(256);
    pssm_proj_kernel<<<grid, block, 0, stream>>>(x, W, bias, out);
}